// Round 13
// baseline (7426.099 us; speedup 1.0000x reference)
//
#include <hip/hip_runtime.h>

// Inputs f32, outputs f32. Value chain f64 (f32 chain noise -> top-k rank
// swaps, R4); conv3 STATS pass f32 (1M-pixel averages wash out rounding, R12);
// conv weights f32 with per-use cvt (f64 weights thrash L1, R7/R9); z2 staged
// (R11; FETCH shows nS=4096). R13: dedicated staged conv3 kernels (6-row
// strips, LDS=h2S only 36KB -> 4 blocks/CU, weight-cvt amortized x6 rows) +
// k_mlp ILP (merged halves, 8 FMA chains).

// ---- f32 weight block (float offsets into ws) ----
#define WS_W1   0
#define WS_B1   288
#define WS_W2   320
#define WS_B2   18752
#define WS_W3   18816
#define WS_B3   92544
#define WS_FCW  92672
#define WS_FCB  125440
#define WS_G1W  125696
#define WS_G1B  256768
#define WS_L1G  257280
#define WS_L1B  257792
#define WS_G2W  258304
#define WS_G2B  520448
#define WS_L2G  520960
#define WS_L2B  521472
#define WS_G3W  521984
#define WS_G3B  526080
// ---- f64 region (double offsets into ws) ----
#define D_ACC1  263044
#define D_ACC2  (D_ACC1 + 4096)
#define D_ACC3  (D_ACC2 + 8192)
#define D_FEAT  (D_ACC3 + 16384)
#define D_AFF1  (D_FEAT + 524288)
#define D_AFF2  (D_AFF1 + 64)
#define D_AFF3  (D_AFF2 + 128)
#define D_ZN    553408        // doubles zeroed from D_ACC1; region ends at byte 6,531,616
// ---- z2 staging: first 512-aligned byte AFTER the f64 region ----
#define Z2_OFF_B 6532096ull

// ---------------- zero f64 accumulators ----------------
__global__ __launch_bounds__(256) void k_zero(double* __restrict__ dst){
  int i = blockIdx.x*256 + threadIdx.x;
  if(i < D_ZN) dst[i] = 0.0;
}

// ---------------- weight gather-copy (f32) ----------------
struct WP { const float* p[18]; };

__global__ __launch_bounds__(256) void k_cvt(WP wp, float* __restrict__ dst){
  const int segn[18] = {288,32,18432,64,73728,128,32768,256,131072,512,512,512,262144,512,512,512,4096,8};
  const int sego[18] = {WS_W1,WS_B1,WS_W2,WS_B2,WS_W3,WS_B3,WS_FCW,WS_FCB,WS_G1W,WS_G1B,
                        WS_L1G,WS_L1B,WS_G2W,WS_G2B,WS_L2G,WS_L2B,WS_G3W,WS_G3B};
  int s = blockIdx.y;
  int i = blockIdx.x*256 + threadIdx.x;
  if(i < segn[s]) dst[sego[s]+i] = wp.p[s][i];
}

// ---------------- finalize BN stats ----------------
__global__ __launch_bounds__(64) void k_fin(const double* __restrict__ acc, int C,
                                            const float* __restrict__ gam, const float* __restrict__ bet,
                                            double* __restrict__ aff){
  int c = blockIdx.x, t = threadIdx.x;
  double s = acc[t*2*C + c*2];
  double q = acc[t*2*C + c*2 + 1];
  #pragma unroll
  for(int off=32;off;off>>=1){ s += __shfl_down(s,off); q += __shfl_down(q,off); }
  if(t==0){
    double m = s*(1.0/1048576.0);
    double v = q*(1.0/1048576.0) - m*m;
    double sc = (double)gam[c] / sqrt(v + 1e-5);
    aff[2*c]   = sc;
    aff[2*c+1] = (double)bet[c] - m*sc;
  }
}

// ---------------- pass 1: conv1 raw stats ----------------
__global__ __launch_bounds__(256) void k_p1(const float* __restrict__ x, const float* __restrict__ wf,
                                            double* __restrict__ acc1){
  __shared__ float xp[324];
  __shared__ double red[4][32][2];
  int p = blockIdx.x, t = threadIdx.x;
  for(int i=t;i<324;i+=256) xp[i]=0.f;
  __syncthreads();
  int py=t>>4, px=t&15;
  xp[(py+1)*18 + px + 1] = x[(size_t)p*256+t];
  __syncthreads();
  double nb[9];
  #pragma unroll
  for(int j=0;j<9;j++) nb[j] = (double)xp[(py+j/3)*18 + px + (j%3)];
  int wave=t>>6, lane=t&63;
  for(int c=0;c<32;c++){
    double a = (double)wf[WS_B1+c];
    #pragma unroll
    for(int j=0;j<9;j++) a = fma(nb[j], (double)wf[WS_W1+c*9+j], a);
    double s=a, q=a*a;
    #pragma unroll
    for(int off=32;off;off>>=1){ s+=__shfl_down(s,off); q+=__shfl_down(q,off); }
    if(lane==0){ red[wave][c][0]=s; red[wave][c][1]=q; }
  }
  __syncthreads();
  if(t<64){
    int c=t>>1, st=t&1;
    double v = red[0][c][st]+red[1][c][st]+red[2][c][st]+red[3][c][st];
    atomicAdd(&acc1[(p&63)*64 + c*2 + st], v);
  }
}

// ---------------- pass 2: conv1 -> bn1relu -> conv2 stats (+ z2 store for p<nS) ----------------
__global__ __launch_bounds__(256) void k_p2(const float* __restrict__ x, const float* __restrict__ wf,
                                            const double* __restrict__ aff1, double* __restrict__ acc2,
                                            float* __restrict__ z2, int nS){
  __shared__ float xp[324];
  __shared__ float h1f[32*324];
  int p=blockIdx.x, t=threadIdx.x;
  for(int i=t;i<324;i+=256) xp[i]=0.f;
  for(int i=t;i<32*324;i+=256) h1f[i]=0.f;
  __syncthreads();
  int py=t>>4, px=t&15;
  xp[(py+1)*18 + px + 1] = x[(size_t)p*256+t];
  __syncthreads();
  {
    double nb[9];
    #pragma unroll
    for(int j=0;j<9;j++) nb[j] = (double)xp[(py+j/3)*18 + px + (j%3)];
    for(int c=0;c<32;c++){
      double a = (double)wf[WS_B1+c];
      #pragma unroll
      for(int j=0;j<9;j++) a = fma(nb[j], (double)wf[WS_W1+c*9+j], a);
      h1f[c*324 + (py+1)*18 + (px+1)] = (float)fmax(aff1[2*c]*a + aff1[2*c+1], 0.0);
    }
  }
  __syncthreads();
  int col=t&15, og=t>>4;
  bool wr = (p < nS);
  double sT[4]={0,0,0,0}, qT[4]={0,0,0,0};
  #pragma unroll 1
  for(int half=0; half<2; ++half){
    double acc[4][8];
    #pragma unroll
    for(int o=0;o<4;o++){
      double bv = (double)wf[WS_B2 + og*4 + o];
      #pragma unroll
      for(int r=0;r<8;r++) acc[o][r]=bv;
    }
    #pragma unroll 1
    for(int ic=0; ic<32; ++ic){
      const float* wrow = wf + WS_W2 + (og*4*32 + ic)*9;
      #pragma unroll
      for(int j=0;j<9;j++){
        double w4[4];
        #pragma unroll
        for(int o=0;o<4;o++) w4[o] = (double)wrow[o*288 + j];
        int dy=j/3, dx=j%3;
        #pragma unroll
        for(int r=0;r<8;r++){
          double m = (double)h1f[ic*324 + (half*8 + r + dy)*18 + col + dx];
          #pragma unroll
          for(int o=0;o<4;o++) acc[o][r] = fma(m, w4[o], acc[o][r]);
        }
      }
    }
    #pragma unroll
    for(int o=0;o<4;o++){
      #pragma unroll
      for(int r=0;r<8;r++){ sT[o]+=acc[o][r]; qT[o]+=acc[o][r]*acc[o][r]; }
      if(wr){
        int c = og*4+o;
        #pragma unroll
        for(int r=0;r<8;r++) z2[((size_t)p*64+c)*256 + (half*8+r)*16 + col] = (float)acc[o][r];
      }
    }
  }
  #pragma unroll
  for(int o=0;o<4;o++){
    double s=sT[o], q=qT[o];
    #pragma unroll
    for(int off=8;off;off>>=1){ s+=__shfl_down(s,off,16); q+=__shfl_down(q,off,16); }
    if(col==0){
      int c = og*4+o;
      atomicAdd(&acc2[(p&63)*128 + c*2 + 0], s);
      atomicAdd(&acc2[(p&63)*128 + c*2 + 1], q);
    }
  }
}

// ========= STAGED conv3 stats (f32): 6-row strips, LDS = h2S only =========
__global__ __launch_bounds__(256) void k_cs(const float* __restrict__ wf, const double* __restrict__ aff2,
                                            double* __restrict__ acc3, const float* __restrict__ z2){
  __shared__ float h2S[64*144];   // [ch][8 input rows][18 cols]
  int bid=blockIdx.x, t=threadIdx.x;
  int p = bid/3, s = bid - p*3;
  int r0 = s*6;
  for(int i=t;i<64*144;i+=256) h2S[i]=0.f;
  __syncthreads();
  for(int i=t;i<8192;i+=256){
    int ch=i>>7, rem=i&127, lr=rem>>4, c2=rem&15;
    int gr = r0-1+lr;
    if(gr>=0 && gr<16){
      float zv = z2[((size_t)p*64+ch)*256 + gr*16 + c2];
      h2S[ch*144 + lr*18 + c2+1] = fmaxf(fmaf((float)aff2[2*ch], zv, (float)aff2[2*ch+1]), 0.f);
    }
  }
  __syncthreads();
  int col=t&15, og=t>>4;
  #pragma unroll 1
  for(int ot=0; ot<2; ++ot){
    int ocb = ot*64 + og*4;
    float acc[4][6];
    #pragma unroll
    for(int o=0;o<4;o++){
      float bv = wf[WS_B3 + ocb + o];
      #pragma unroll
      for(int r=0;r<6;r++) acc[o][r]=bv;
    }
    #pragma unroll 1
    for(int ic=0; ic<64; ++ic){
      float a[8][3];
      #pragma unroll
      for(int lr=0; lr<8; ++lr){
        #pragma unroll
        for(int dx=0; dx<3; ++dx) a[lr][dx] = h2S[ic*144 + lr*18 + col + dx];
      }
      const float* wrow = wf + WS_W3 + ((size_t)ocb*64 + ic)*9;
      #pragma unroll
      for(int o=0;o<4;o++){
        #pragma unroll
        for(int j=0;j<9;j++){
          float w = wrow[o*576 + j];
          #pragma unroll
          for(int r=0;r<6;r++) acc[o][r] = fmaf(a[r + j/3][j%3], w, acc[o][r]);
        }
      }
    }
    #pragma unroll
    for(int o=0;o<4;o++){
      double sS=0.0, qS=0.0;
      #pragma unroll
      for(int r=0;r<6;r++){
        if(r0 + r < 16){ double v=(double)acc[o][r]; sS+=v; qS+=v*v; }
      }
      #pragma unroll
      for(int off=8; off; off>>=1){ sS += __shfl_down(sS, off, 16); qS += __shfl_down(qS, off, 16); }
      if(col==0){
        int c = ocb+o;
        atomicAdd(&acc3[(bid&63)*256 + c*2 + 0], sS);
        atomicAdd(&acc3[(bid&63)*256 + c*2 + 1], qS);
      }
    }
  }
}

// ========= STAGED conv3 feat (f64 value chain): 6-row strips =========
__global__ __launch_bounds__(256) void k_cf(const float* __restrict__ wf, const double* __restrict__ aff2,
                                            const double* __restrict__ aff3, double* __restrict__ feat,
                                            const float* __restrict__ z2){
  __shared__ float h2S[64*144];
  int bid=blockIdx.x, t=threadIdx.x;
  int p = bid/3, s = bid - p*3;
  int r0 = s*6;
  for(int i=t;i<64*144;i+=256) h2S[i]=0.f;
  __syncthreads();
  for(int i=t;i<8192;i+=256){
    int ch=i>>7, rem=i&127, lr=rem>>4, c2=rem&15;
    int gr = r0-1+lr;
    if(gr>=0 && gr<16){
      double zv = (double)z2[((size_t)p*64+ch)*256 + gr*16 + c2];
      h2S[ch*144 + lr*18 + c2+1] = (float)fmax(fma(aff2[2*ch], zv, aff2[2*ch+1]), 0.0);
    }
  }
  __syncthreads();
  int col=t&15, og=t>>4;
  #pragma unroll 1
  for(int ot=0; ot<2; ++ot){
    int ocb = ot*64 + og*4;
    double acc[4][6];
    #pragma unroll
    for(int o=0;o<4;o++){
      double bv = (double)wf[WS_B3 + ocb + o];
      #pragma unroll
      for(int r=0;r<6;r++) acc[o][r]=bv;
    }
    #pragma unroll 1
    for(int ic=0; ic<64; ++ic){
      double a[8][3];
      #pragma unroll
      for(int lr=0; lr<8; ++lr){
        #pragma unroll
        for(int dx=0; dx<3; ++dx) a[lr][dx] = (double)h2S[ic*144 + lr*18 + col + dx];
      }
      const float* wrow = wf + WS_W3 + ((size_t)ocb*64 + ic)*9;
      #pragma unroll
      for(int o=0;o<4;o++){
        #pragma unroll
        for(int j=0;j<9;j++){
          double w = (double)wrow[o*576 + j];
          #pragma unroll
          for(int r=0;r<6;r++) acc[o][r] = fma(a[r + j/3][j%3], w, acc[o][r]);
        }
      }
    }
    #pragma unroll
    for(int o=0;o<4;o++){
      int c = ocb+o;
      double sc=aff3[2*c], sh=aff3[2*c+1];
      double sv = 0.0;
      #pragma unroll
      for(int r=0;r<6;r++){
        if(r0 + r < 16) sv += fmax(fma(sc, acc[o][r], sh), 0.0);
      }
      #pragma unroll
      for(int off=8; off; off>>=1) sv += __shfl_down(sv, off, 16);
      if(col==0) atomicAdd(&feat[(size_t)p*128 + c], sv);
    }
  }
}

// ========= FALLBACK recompute conv3 stats (f32), patches p0.. =========
__global__ __launch_bounds__(256) void k_stat3(const float* __restrict__ x, const float* __restrict__ wf,
                                               const double* __restrict__ aff1, const double* __restrict__ aff2,
                                               double* __restrict__ acc3, int p0){
  __shared__ float xp[324];
  __shared__ float h1S[32*144];
  __shared__ float h2S[64*108];
  int bid=blockIdx.x, t=threadIdx.x;
  int p = p0 + (bid>>2), r0 = (bid&3)*4;
  for(int i=t;i<64*108;i+=256) h2S[i]=0.f;
  for(int i=t;i<324;i+=256) xp[i]=0.f;
  for(int i=t;i<32*144;i+=256) h1S[i]=0.f;
  __syncthreads();
  { int py=t>>4, px=t&15; xp[(py+1)*18 + px + 1] = x[(size_t)p*256+t]; }
  __syncthreads();
  {
    int rr=t>>5, cw=t&31, col=cw&15, half=cw>>4;
    int p1 = r0-1+rr;
    if(p1>=1 && p1<=16){
      float nb[9];
      #pragma unroll
      for(int j=0;j<9;j++) nb[j] = xp[(p1-1+j/3)*18 + col + (j%3)];
      for(int k=0;k<16;k++){
        int c = half*16+k;
        float a = wf[WS_B1+c];
        #pragma unroll
        for(int j=0;j<9;j++) a = fmaf(nb[j], wf[WS_W1+c*9+j], a);
        h1S[c*144 + rr*18 + col+1] = fmaxf((float)aff1[2*c]*a + (float)aff1[2*c+1], 0.f);
      }
    }
  }
  __syncthreads();
  {
    int col=t&15, g=t>>4;
    float a24[4][6];
    #pragma unroll
    for(int o=0;o<4;o++){
      float bv = wf[WS_B2+g*4+o];
      #pragma unroll
      for(int b2=0;b2<6;b2++) a24[o][b2] = bv;
    }
    #pragma unroll 1
    for(int ic=0;ic<32;ic++){
      const float* wrow = wf + WS_W2 + (g*4*32 + ic)*9;
      #pragma unroll
      for(int j=0;j<9;j++){
        float w4[4];
        #pragma unroll
        for(int o=0;o<4;o++) w4[o] = wrow[o*288 + j];
        int dy=j/3, dx=j%3;
        #pragma unroll
        for(int b2=0;b2<6;b2++){
          float m = h1S[ic*144 + (b2+dy)*18 + col + dx];
          #pragma unroll
          for(int o=0;o<4;o++) a24[o][b2] = fmaf(m, w4[o], a24[o][b2]);
        }
      }
    }
    #pragma unroll
    for(int b2=0;b2<6;b2++){
      int p2 = r0+b2;
      if(p2>=1 && p2<=16){
        #pragma unroll
        for(int o=0;o<4;o++){
          int c=g*4+o;
          h2S[c*108 + b2*18 + col+1] = fmaxf((float)aff2[2*c]*a24[o][b2] + (float)aff2[2*c+1], 0.f);
        }
      }
    }
  }
  __syncthreads();
  {
    int col = t & 15, og = t >> 4;
    float acc[8][4];
    #pragma unroll
    for(int o=0;o<8;o++){
      float bv = wf[WS_B3 + og*8 + o];
      #pragma unroll
      for(int r=0;r<4;r++) acc[o][r] = bv;
    }
    #pragma unroll 1
    for(int ic=0; ic<64; ++ic){
      float a[6][3];
      #pragma unroll
      for(int rr=0; rr<6; ++rr){
        #pragma unroll
        for(int dx=0; dx<3; ++dx) a[rr][dx] = h2S[ic*108 + rr*18 + col + dx];
      }
      const float* wrow = wf + WS_W3 + (og*8*64 + ic)*9;
      #pragma unroll
      for(int o=0;o<8;o++){
        #pragma unroll
        for(int j=0;j<9;j++){
          float w = wrow[o*576 + j];
          #pragma unroll
          for(int r=0;r<4;r++) acc[o][r] = fmaf(a[r + j/3][j%3], w, acc[o][r]);
        }
      }
    }
    #pragma unroll
    for(int o=0;o<8;o++){
      double s=0.0, q=0.0;
      #pragma unroll
      for(int r=0;r<4;r++){ double v=(double)acc[o][r]; s+=v; q+=v*v; }
      #pragma unroll
      for(int off=8; off; off>>=1){ s += __shfl_down(s, off, 16); q += __shfl_down(q, off, 16); }
      if(col==0){
        int c = og*8+o;
        atomicAdd(&acc3[(bid&63)*256 + c*2 + 0], s);
        atomicAdd(&acc3[(bid&63)*256 + c*2 + 1], q);
      }
    }
  }
}

// ========= FALLBACK recompute conv3 feat (f64), patches p0.. =========
__global__ __launch_bounds__(256) void k_p34(const float* __restrict__ x, const float* __restrict__ wf,
                                             const double* __restrict__ aff1, const double* __restrict__ aff2,
                                             const double* __restrict__ aff3, double* __restrict__ outp,
                                             int p0){
  __shared__ float xp[324];
  __shared__ float h1S[32*144];
  __shared__ float h2S[64*108];
  int bid=blockIdx.x, t=threadIdx.x;
  int p = p0 + (bid>>2), r0 = (bid&3)*4;
  for(int i=t;i<64*108;i+=256) h2S[i]=0.f;
  for(int i=t;i<324;i+=256) xp[i]=0.f;
  for(int i=t;i<32*144;i+=256) h1S[i]=0.f;
  __syncthreads();
  { int py=t>>4, px=t&15; xp[(py+1)*18 + px + 1] = x[(size_t)p*256+t]; }
  __syncthreads();
  {
    int rr=t>>5, cw=t&31, col=cw&15, half=cw>>4;
    int p1 = r0-1+rr;
    if(p1>=1 && p1<=16){
      double nb[9];
      #pragma unroll
      for(int j=0;j<9;j++) nb[j] = (double)xp[(p1-1+j/3)*18 + col + (j%3)];
      for(int k=0;k<16;k++){
        int c = half*16+k;
        double a = (double)wf[WS_B1+c];
        #pragma unroll
        for(int j=0;j<9;j++) a = fma(nb[j], (double)wf[WS_W1+c*9+j], a);
        h1S[c*144 + rr*18 + col+1] = (float)fmax(aff1[2*c]*a + aff1[2*c+1], 0.0);
      }
    }
  }
  __syncthreads();
  {
    int col=t&15, g=t>>4;
    double a24[4][6];
    #pragma unroll
    for(int o=0;o<4;o++){
      double bv = (double)wf[WS_B2+g*4+o];
      #pragma unroll
      for(int b2=0;b2<6;b2++) a24[o][b2] = bv;
    }
    #pragma unroll 1
    for(int ic=0;ic<32;ic++){
      const float* wrow = wf + WS_W2 + (g*4*32 + ic)*9;
      #pragma unroll
      for(int j=0;j<9;j++){
        double w4[4];
        #pragma unroll
        for(int o=0;o<4;o++) w4[o] = (double)wrow[o*288 + j];
        int dy=j/3, dx=j%3;
        #pragma unroll
        for(int b2=0;b2<6;b2++){
          double m = (double)h1S[ic*144 + (b2+dy)*18 + col + dx];
          #pragma unroll
          for(int o=0;o<4;o++) a24[o][b2] = fma(m, w4[o], a24[o][b2]);
        }
      }
    }
    #pragma unroll
    for(int b2=0;b2<6;b2++){
      int p2 = r0+b2;
      if(p2>=1 && p2<=16){
        #pragma unroll
        for(int o=0;o<4;o++){
          int c=g*4+o;
          h2S[c*108 + b2*18 + col+1] = (float)fmax(aff2[2*c]*a24[o][b2] + aff2[2*c+1], 0.0);
        }
      }
    }
  }
  __syncthreads();
  {
    int col = t & 15, og = t >> 4;
    double acc[8][4];
    #pragma unroll
    for(int o=0;o<8;o++){
      double bv = (double)wf[WS_B3 + og*8 + o];
      #pragma unroll
      for(int r=0;r<4;r++) acc[o][r] = bv;
    }
    #pragma unroll 1
    for(int ic=0; ic<64; ++ic){
      double a[6][3];
      #pragma unroll
      for(int rr=0; rr<6; ++rr){
        #pragma unroll
        for(int dx=0; dx<3; ++dx) a[rr][dx] = (double)h2S[ic*108 + rr*18 + col + dx];
      }
      const float* wrow = wf + WS_W3 + (og*8*64 + ic)*9;
      #pragma unroll
      for(int o=0;o<8;o++){
        #pragma unroll
        for(int j=0;j<9;j++){
          double w = (double)wrow[o*576 + j];
          #pragma unroll
          for(int r=0;r<4;r++) acc[o][r] = fma(a[r + j/3][j%3], w, acc[o][r]);
        }
      }
    }
    #pragma unroll
    for(int o=0;o<8;o++){
      int c = og*8+o;
      double sc=aff3[2*c], sh=aff3[2*c+1];
      double s = 0.0;
      #pragma unroll
      for(int r=0;r<4;r++) s += fmax(fma(sc, acc[o][r], sh), 0.0);
      #pragma unroll
      for(int off=8; off; off>>=1) s += __shfl_down(s, off, 16);
      if(col==0) atomicAdd(&outp[(size_t)p*128 + c], s);
    }
  }
}

// ---------------- LN + relu on [4][512] f64 LDS buffer ----------------
__device__ __forceinline__ void ln_relu4(double* buf, const float* __restrict__ g, const float* __restrict__ b,
                                         double* lnm, double* lnr, int t){
  int r=t>>6, j=t&63;
  double s=0.0, q=0.0;
  for(int k=j;k<512;k+=64){ double v=buf[r*512+k]; s+=v; q+=v*v; }
  #pragma unroll
  for(int off=32;off;off>>=1){ s+=__shfl_down(s,off); q+=__shfl_down(q,off); }
  if(j==0){
    double m = s*(1.0/512.0);
    double v = q*(1.0/512.0) - m*m;
    lnm[r]=m; lnr[r]=1.0/sqrt(v + 1e-5);
  }
  __syncthreads();
  for(int i=t;i<2048;i+=256){
    int r2=i>>9, k=i&511;
    double v=(buf[i]-lnm[r2])*lnr[r2]*(double)g[k]+(double)b[k];
    buf[i]=fmax(v,0.0);
  }
  __syncthreads();
}

// ---------------- MLP head (f64): 4 rows/block, merged halves for ILP ----------------
__global__ __launch_bounds__(256) void k_mlp(const float* __restrict__ wf, const double* __restrict__ feat,
                                             float* __restrict__ assign_out){
  int r0 = blockIdx.x*4, t = threadIdx.x;
  __shared__ double f0[4*128];
  __shared__ double f1[4*256];
  __shared__ double f2[4*512];
  __shared__ double f3[4*512];
  __shared__ double lnm[4], lnr[4];
  __shared__ double lg[4][8];

  for(int i=t;i<512;i+=256) f0[i] = feat[(size_t)r0*128 + i] * (1.0/256.0);
  __syncthreads();
  // fc: 128 -> 256
  {
    double acc[4];
    double bv = (double)wf[WS_FCB + t];
    #pragma unroll
    for(int r=0;r<4;r++) acc[r]=bv;
    for(int k=0;k<128;k++){
      double wv = (double)wf[WS_FCW + t*128 + k];
      #pragma unroll
      for(int r=0;r<4;r++) acc[r]=fma(wv, f0[r*128+k], acc[r]);
    }
    #pragma unroll
    for(int r=0;r<4;r++) f1[r*256+t]=acc[r];
  }
  __syncthreads();
  // g1: 256 -> 512 (both halves per k -> 8 FMA chains)
  {
    double a0[4], a1[4];
    double bv0=(double)wf[WS_G1B+t], bv1=(double)wf[WS_G1B+t+256];
    #pragma unroll
    for(int r=0;r<4;r++){ a0[r]=bv0; a1[r]=bv1; }
    for(int k=0;k<256;k++){
      double wv0=(double)wf[WS_G1W + t*256 + k];
      double wv1=(double)wf[WS_G1W + (t+256)*256 + k];
      #pragma unroll
      for(int r=0;r<4;r++){
        double fv = f1[r*256+k];
        a0[r]=fma(wv0, fv, a0[r]);
        a1[r]=fma(wv1, fv, a1[r]);
      }
    }
    #pragma unroll
    for(int r=0;r<4;r++){ f2[r*512+t]=a0[r]; f2[r*512+t+256]=a1[r]; }
  }
  __syncthreads();
  ln_relu4(f2, wf+WS_L1G, wf+WS_L1B, lnm, lnr, t);
  // g2: 512 -> 512 (both halves per k)
  {
    double a0[4], a1[4];
    double bv0=(double)wf[WS_G2B+t], bv1=(double)wf[WS_G2B+t+256];
    #pragma unroll
    for(int r=0;r<4;r++){ a0[r]=bv0; a1[r]=bv1; }
    for(int k=0;k<512;k++){
      double wv0=(double)wf[WS_G2W + t*512 + k];
      double wv1=(double)wf[WS_G2W + (t+256)*512 + k];
      #pragma unroll
      for(int r=0;r<4;r++){
        double fv = f2[r*512+k];
        a0[r]=fma(wv0, fv, a0[r]);
        a1[r]=fma(wv1, fv, a1[r]);
      }
    }
    #pragma unroll
    for(int r=0;r<4;r++){ f3[r*512+t]=a0[r]; f3[r*512+t+256]=a1[r]; }
  }
  __syncthreads();
  ln_relu4(f3, wf+WS_L2G, wf+WS_L2B, lnm, lnr, t);
  {
    int r=t>>6, j=t&63;
    double pl[8];
    #pragma unroll
    for(int g=0;g<8;g++){
      double s=0.0;
      for(int k=j;k<512;k+=64) s = fma(f3[r*512+k], (double)wf[WS_G3W + g*512 + k], s);
      pl[g]=s;
    }
    #pragma unroll
    for(int off=32;off;off>>=1){
      #pragma unroll
      for(int g=0;g<8;g++) pl[g] += __shfl_down(pl[g], off);
    }
    if(j==0){
      #pragma unroll
      for(int g=0;g<8;g++) lg[r][g] = (pl[g] + (double)wf[WS_G3B+g]) * 2.0; // /TEMP
    }
  }
  __syncthreads();
  if(t<4){
    double m=-1e300;
    #pragma unroll
    for(int g=0;g<8;g++) m = fmax(m, lg[t][g]);
    double e[8], s=0.0;
    #pragma unroll
    for(int g=0;g<8;g++){ e[g]=exp(lg[t][g]-m); s+=e[g]; }
    double inv = 1.0/s;
    int row = r0 + t;
    #pragma unroll
    for(int g=0;g<8;g++) assign_out[row*8+g] = (float)(e[g]*inv);
  }
}

// ---------------- top-32 per (b,g) + gather*scale ----------------
__global__ __launch_bounds__(256) void k_topk(const float* __restrict__ assign, const float* __restrict__ x,
                                              float* __restrict__ out){
  int b = blockIdx.x >> 3, g = blockIdx.x & 7, t = threadIdx.x;
  __shared__ float v[256];
  __shared__ int   id[256];
  v[t] = assign[(b*256+t)*8 + g];
  id[t] = t;
  __syncthreads();
  for(int k=2;k<=256;k<<=1){
    for(int j=k>>1;j>0;j>>=1){
      int ixj = t ^ j;
      if(ixj > t){
        float va=v[t], vb=v[ixj];
        int ia=id[t], ib=id[ixj];
        bool aBefore = (va > vb) || (va == vb && ia < ib);
        bool up = ((t & k) == 0);
        if(up != aBefore){ v[t]=vb; v[ixj]=va; id[t]=ib; id[ixj]=ia; }
      }
      __syncthreads();
    }
  }
  __shared__ float tv[32];
  __shared__ int   ti[32];
  if(t<32){ tv[t]=v[t]; ti[t]=id[t]; }
  __syncthreads();
  const float* xb = x + (size_t)b*65536;
  float* ob = out + (size_t)(b*8+g)*8192;
  for(int i=t;i<8192;i+=256){
    int k=i>>8, pix=i&255;
    ob[i] = tv[k] * xb[ti[k]*256 + pix];
  }
}

// ---------------- launcher ----------------
extern "C" void kernel_launch(void* const* d_in, const int* in_sizes, int n_in,
                              void* d_out, int out_size, void* d_ws, size_t ws_size,
                              hipStream_t stream){
  const float* x = (const float*)d_in[0];
  float*  ws  = (float*)d_ws;
  double* dws = (double*)d_ws;
  float* out = (float*)d_out;
  float* assign_out = out + 1048576;
  float* z2 = (float*)((char*)d_ws + Z2_OFF_B);

  int nS = 0;
  if(ws_size > Z2_OFF_B + 65536){
    unsigned long long avail = (unsigned long long)ws_size - Z2_OFF_B;
    unsigned long long n = avail / 65536ull;
    nS = (n > 4096ull) ? 4096 : (int)n;
  }
  int nR = 4096 - nS;   // patches needing recompute fallback

  const float* g1=(const float*)d_in[3];  const float* b1=(const float*)d_in[4];
  const float* g2=(const float*)d_in[7];  const float* b2=(const float*)d_in[8];
  const float* g3=(const float*)d_in[11]; const float* b3=(const float*)d_in[12];

  WP wp;
  const int map[18] = {1,2,5,6,9,10,13,14,15,16,17,18,19,20,21,22,23,24};
  for(int i=0;i<18;i++) wp.p[i] = (const float*)d_in[map[i]];

  k_zero <<<2162, 256, 0, stream>>>(dws + D_ACC1);
  k_cvt  <<<dim3(1024,18), 256, 0, stream>>>(wp, ws);
  k_p1   <<<4096, 256, 0, stream>>>(x, ws, dws+D_ACC1);
  k_fin  <<<32, 64, 0, stream>>>(dws+D_ACC1, 32, g1, b1, dws+D_AFF1);
  k_p2   <<<4096, 256, 0, stream>>>(x, ws, dws+D_AFF1, dws+D_ACC2, z2, nS);
  k_fin  <<<64, 64, 0, stream>>>(dws+D_ACC2, 64, g2, b2, dws+D_AFF2);
  if(nS > 0) k_cs   <<<3*nS, 256, 0, stream>>>(ws, dws+D_AFF2, dws+D_ACC3, z2);
  if(nR > 0) k_stat3<<<4*nR, 256, 0, stream>>>(x, ws, dws+D_AFF1, dws+D_AFF2, dws+D_ACC3, nS);
  k_fin  <<<128, 64, 0, stream>>>(dws+D_ACC3, 128, g3, b3, dws+D_AFF3);
  if(nS > 0) k_cf  <<<3*nS, 256, 0, stream>>>(ws, dws+D_AFF2, dws+D_AFF3, dws+D_FEAT, z2);
  if(nR > 0) k_p34 <<<4*nR, 256, 0, stream>>>(x, ws, dws+D_AFF1, dws+D_AFF2, dws+D_AFF3, dws+D_FEAT, nS);
  k_mlp  <<<1024, 256, 0, stream>>>(ws, dws+D_FEAT, assign_out);
  k_topk <<<128, 256, 0, stream>>>(assign_out, x, out);
}

// Round 14
// 5891.482 us; speedup vs baseline: 1.2605x; 1.2605x over previous
//
#include <hip/hip_runtime.h>

// Inputs f32, outputs f32. BN affines + MLP + softmax in f64; conv3 passes
// (stats AND feat) in f32: the 256-pixel spatial mean shrinks f32 conv noise
// to ~1e-8 rel on feat, below the ~6e-8 z2-f32-staging perturbation already
// survived in R11/R13 (rank gaps at all 128 boundaries exceed it). Value
// chain conv1/conv2 stay f64 (R4: full-f32 chain -> rank swaps). Conv weights
// f32 (f64 weights thrash L1: R7/R9). z2 staged (R11). k_mlp = R12 version.

// ---- f32 weight block (float offsets into ws) ----
#define WS_W1   0
#define WS_B1   288
#define WS_W2   320
#define WS_B2   18752
#define WS_W3   18816
#define WS_B3   92544
#define WS_FCW  92672
#define WS_FCB  125440
#define WS_G1W  125696
#define WS_G1B  256768
#define WS_L1G  257280
#define WS_L1B  257792
#define WS_G2W  258304
#define WS_G2B  520448
#define WS_L2G  520960
#define WS_L2B  521472
#define WS_G3W  521984
#define WS_G3B  526080
// ---- f64 region (double offsets into ws) ----
#define D_ACC1  263044
#define D_ACC2  (D_ACC1 + 4096)
#define D_ACC3  (D_ACC2 + 8192)
#define D_FEAT  (D_ACC3 + 16384)
#define D_AFF1  (D_FEAT + 524288)
#define D_AFF2  (D_AFF1 + 64)
#define D_AFF3  (D_AFF2 + 128)
#define D_ZN    553408        // doubles zeroed from D_ACC1; region ends at byte 6,531,616
// ---- z2 staging: first 512-aligned byte AFTER the f64 region ----
#define Z2_OFF_B 6532096ull

// ---------------- zero f64 accumulators ----------------
__global__ __launch_bounds__(256) void k_zero(double* __restrict__ dst){
  int i = blockIdx.x*256 + threadIdx.x;
  if(i < D_ZN) dst[i] = 0.0;
}

// ---------------- weight gather-copy (f32) ----------------
struct WP { const float* p[18]; };

__global__ __launch_bounds__(256) void k_cvt(WP wp, float* __restrict__ dst){
  const int segn[18] = {288,32,18432,64,73728,128,32768,256,131072,512,512,512,262144,512,512,512,4096,8};
  const int sego[18] = {WS_W1,WS_B1,WS_W2,WS_B2,WS_W3,WS_B3,WS_FCW,WS_FCB,WS_G1W,WS_G1B,
                        WS_L1G,WS_L1B,WS_G2W,WS_G2B,WS_L2G,WS_L2B,WS_G3W,WS_G3B};
  int s = blockIdx.y;
  int i = blockIdx.x*256 + threadIdx.x;
  if(i < segn[s]) dst[sego[s]+i] = wp.p[s][i];
}

// ---------------- finalize BN stats ----------------
__global__ __launch_bounds__(64) void k_fin(const double* __restrict__ acc, int C,
                                            const float* __restrict__ gam, const float* __restrict__ bet,
                                            double* __restrict__ aff){
  int c = blockIdx.x, t = threadIdx.x;
  double s = acc[t*2*C + c*2];
  double q = acc[t*2*C + c*2 + 1];
  #pragma unroll
  for(int off=32;off;off>>=1){ s += __shfl_down(s,off); q += __shfl_down(q,off); }
  if(t==0){
    double m = s*(1.0/1048576.0);
    double v = q*(1.0/1048576.0) - m*m;
    double sc = (double)gam[c] / sqrt(v + 1e-5);
    aff[2*c]   = sc;
    aff[2*c+1] = (double)bet[c] - m*sc;
  }
}

// ---------------- pass 1: conv1 raw stats ----------------
__global__ __launch_bounds__(256) void k_p1(const float* __restrict__ x, const float* __restrict__ wf,
                                            double* __restrict__ acc1){
  __shared__ float xp[324];
  __shared__ double red[4][32][2];
  int p = blockIdx.x, t = threadIdx.x;
  for(int i=t;i<324;i+=256) xp[i]=0.f;
  __syncthreads();
  int py=t>>4, px=t&15;
  xp[(py+1)*18 + px + 1] = x[(size_t)p*256+t];
  __syncthreads();
  double nb[9];
  #pragma unroll
  for(int j=0;j<9;j++) nb[j] = (double)xp[(py+j/3)*18 + px + (j%3)];
  int wave=t>>6, lane=t&63;
  for(int c=0;c<32;c++){
    double a = (double)wf[WS_B1+c];
    #pragma unroll
    for(int j=0;j<9;j++) a = fma(nb[j], (double)wf[WS_W1+c*9+j], a);
    double s=a, q=a*a;
    #pragma unroll
    for(int off=32;off;off>>=1){ s+=__shfl_down(s,off); q+=__shfl_down(q,off); }
    if(lane==0){ red[wave][c][0]=s; red[wave][c][1]=q; }
  }
  __syncthreads();
  if(t<64){
    int c=t>>1, st=t&1;
    double v = red[0][c][st]+red[1][c][st]+red[2][c][st]+red[3][c][st];
    atomicAdd(&acc1[(p&63)*64 + c*2 + st], v);
  }
}

// ---------------- pass 2: conv1 -> bn1relu -> conv2 stats (+ z2 store for p<nS) ----------------
__global__ __launch_bounds__(256) void k_p2(const float* __restrict__ x, const float* __restrict__ wf,
                                            const double* __restrict__ aff1, double* __restrict__ acc2,
                                            float* __restrict__ z2, int nS){
  __shared__ float xp[324];
  __shared__ float h1f[32*324];
  int p=blockIdx.x, t=threadIdx.x;
  for(int i=t;i<324;i+=256) xp[i]=0.f;
  for(int i=t;i<32*324;i+=256) h1f[i]=0.f;
  __syncthreads();
  int py=t>>4, px=t&15;
  xp[(py+1)*18 + px + 1] = x[(size_t)p*256+t];
  __syncthreads();
  {
    double nb[9];
    #pragma unroll
    for(int j=0;j<9;j++) nb[j] = (double)xp[(py+j/3)*18 + px + (j%3)];
    for(int c=0;c<32;c++){
      double a = (double)wf[WS_B1+c];
      #pragma unroll
      for(int j=0;j<9;j++) a = fma(nb[j], (double)wf[WS_W1+c*9+j], a);
      h1f[c*324 + (py+1)*18 + (px+1)] = (float)fmax(aff1[2*c]*a + aff1[2*c+1], 0.0);
    }
  }
  __syncthreads();
  int col=t&15, og=t>>4;
  bool wr = (p < nS);
  double sT[4]={0,0,0,0}, qT[4]={0,0,0,0};
  #pragma unroll 1
  for(int half=0; half<2; ++half){
    double acc[4][8];
    #pragma unroll
    for(int o=0;o<4;o++){
      double bv = (double)wf[WS_B2 + og*4 + o];
      #pragma unroll
      for(int r=0;r<8;r++) acc[o][r]=bv;
    }
    #pragma unroll 1
    for(int ic=0; ic<32; ++ic){
      const float* wrow = wf + WS_W2 + (og*4*32 + ic)*9;
      #pragma unroll
      for(int j=0;j<9;j++){
        double w4[4];
        #pragma unroll
        for(int o=0;o<4;o++) w4[o] = (double)wrow[o*288 + j];
        int dy=j/3, dx=j%3;
        #pragma unroll
        for(int r=0;r<8;r++){
          double m = (double)h1f[ic*324 + (half*8 + r + dy)*18 + col + dx];
          #pragma unroll
          for(int o=0;o<4;o++) acc[o][r] = fma(m, w4[o], acc[o][r]);
        }
      }
    }
    #pragma unroll
    for(int o=0;o<4;o++){
      #pragma unroll
      for(int r=0;r<8;r++){ sT[o]+=acc[o][r]; qT[o]+=acc[o][r]*acc[o][r]; }
      if(wr){
        int c = og*4+o;
        #pragma unroll
        for(int r=0;r<8;r++) z2[((size_t)p*64+c)*256 + (half*8+r)*16 + col] = (float)acc[o][r];
      }
    }
  }
  #pragma unroll
  for(int o=0;o<4;o++){
    double s=sT[o], q=qT[o];
    #pragma unroll
    for(int off=8;off;off>>=1){ s+=__shfl_down(s,off,16); q+=__shfl_down(q,off,16); }
    if(col==0){
      int c = og*4+o;
      atomicAdd(&acc2[(p&63)*128 + c*2 + 0], s);
      atomicAdd(&acc2[(p&63)*128 + c*2 + 1], q);
    }
  }
}

// ========= STAGED conv3 stats (f32): 6-row strips, LDS = h2S only =========
__global__ __launch_bounds__(256) void k_cs(const float* __restrict__ wf, const double* __restrict__ aff2,
                                            double* __restrict__ acc3, const float* __restrict__ z2){
  __shared__ float h2S[64*144];   // [ch][8 input rows][18 cols]
  int bid=blockIdx.x, t=threadIdx.x;
  int p = bid/3, s = bid - p*3;
  int r0 = s*6;
  for(int i=t;i<64*144;i+=256) h2S[i]=0.f;
  __syncthreads();
  for(int i=t;i<8192;i+=256){
    int ch=i>>7, rem=i&127, lr=rem>>4, c2=rem&15;
    int gr = r0-1+lr;
    if(gr>=0 && gr<16){
      float zv = z2[((size_t)p*64+ch)*256 + gr*16 + c2];
      h2S[ch*144 + lr*18 + c2+1] = fmaxf(fmaf((float)aff2[2*ch], zv, (float)aff2[2*ch+1]), 0.f);
    }
  }
  __syncthreads();
  int col=t&15, og=t>>4;
  #pragma unroll 1
  for(int ot=0; ot<2; ++ot){
    int ocb = ot*64 + og*4;
    float acc[4][6];
    #pragma unroll
    for(int o=0;o<4;o++){
      float bv = wf[WS_B3 + ocb + o];
      #pragma unroll
      for(int r=0;r<6;r++) acc[o][r]=bv;
    }
    #pragma unroll 1
    for(int ic=0; ic<64; ++ic){
      float a[8][3];
      #pragma unroll
      for(int lr=0; lr<8; ++lr){
        #pragma unroll
        for(int dx=0; dx<3; ++dx) a[lr][dx] = h2S[ic*144 + lr*18 + col + dx];
      }
      const float* wrow = wf + WS_W3 + ((size_t)ocb*64 + ic)*9;
      #pragma unroll
      for(int o=0;o<4;o++){
        #pragma unroll
        for(int j=0;j<9;j++){
          float w = wrow[o*576 + j];
          #pragma unroll
          for(int r=0;r<6;r++) acc[o][r] = fmaf(a[r + j/3][j%3], w, acc[o][r]);
        }
      }
    }
    #pragma unroll
    for(int o=0;o<4;o++){
      double sS=0.0, qS=0.0;
      #pragma unroll
      for(int r=0;r<6;r++){
        if(r0 + r < 16){ double v=(double)acc[o][r]; sS+=v; qS+=v*v; }
      }
      #pragma unroll
      for(int off=8; off; off>>=1){ sS += __shfl_down(sS, off, 16); qS += __shfl_down(qS, off, 16); }
      if(col==0){
        int c = ocb+o;
        atomicAdd(&acc3[(bid&63)*256 + c*2 + 0], sS);
        atomicAdd(&acc3[(bid&63)*256 + c*2 + 1], qS);
      }
    }
  }
}

// ========= STAGED conv3 feat (f32 conv; f64 mean accumulate): 6-row strips =========
__global__ __launch_bounds__(256) void k_cf(const float* __restrict__ wf, const double* __restrict__ aff2,
                                            const double* __restrict__ aff3, double* __restrict__ feat,
                                            const float* __restrict__ z2){
  __shared__ float h2S[64*144];
  int bid=blockIdx.x, t=threadIdx.x;
  int p = bid/3, s = bid - p*3;
  int r0 = s*6;
  for(int i=t;i<64*144;i+=256) h2S[i]=0.f;
  __syncthreads();
  for(int i=t;i<8192;i+=256){
    int ch=i>>7, rem=i&127, lr=rem>>4, c2=rem&15;
    int gr = r0-1+lr;
    if(gr>=0 && gr<16){
      float zv = z2[((size_t)p*64+ch)*256 + gr*16 + c2];
      h2S[ch*144 + lr*18 + c2+1] = fmaxf(fmaf((float)aff2[2*ch], zv, (float)aff2[2*ch+1]), 0.f);
    }
  }
  __syncthreads();
  int col=t&15, og=t>>4;
  #pragma unroll 1
  for(int ot=0; ot<2; ++ot){
    int ocb = ot*64 + og*4;
    float acc[4][6];
    #pragma unroll
    for(int o=0;o<4;o++){
      float bv = wf[WS_B3 + ocb + o];
      #pragma unroll
      for(int r=0;r<6;r++) acc[o][r]=bv;
    }
    #pragma unroll 1
    for(int ic=0; ic<64; ++ic){
      float a[8][3];
      #pragma unroll
      for(int lr=0; lr<8; ++lr){
        #pragma unroll
        for(int dx=0; dx<3; ++dx) a[lr][dx] = h2S[ic*144 + lr*18 + col + dx];
      }
      const float* wrow = wf + WS_W3 + ((size_t)ocb*64 + ic)*9;
      #pragma unroll
      for(int o=0;o<4;o++){
        #pragma unroll
        for(int j=0;j<9;j++){
          float w = wrow[o*576 + j];
          #pragma unroll
          for(int r=0;r<6;r++) acc[o][r] = fmaf(a[r + j/3][j%3], w, acc[o][r]);
        }
      }
    }
    #pragma unroll
    for(int o=0;o<4;o++){
      int c = ocb+o;
      float sc=(float)aff3[2*c], sh=(float)aff3[2*c+1];
      double sv = 0.0;
      #pragma unroll
      for(int r=0;r<6;r++){
        if(r0 + r < 16) sv += (double)fmaxf(fmaf(sc, acc[o][r], sh), 0.f);
      }
      #pragma unroll
      for(int off=8; off; off>>=1) sv += __shfl_down(sv, off, 16);
      if(col==0) atomicAdd(&feat[(size_t)p*128 + c], sv);
    }
  }
}

// ========= FALLBACK recompute conv3 stats (f32), patches p0.. =========
__global__ __launch_bounds__(256) void k_stat3(const float* __restrict__ x, const float* __restrict__ wf,
                                               const double* __restrict__ aff1, const double* __restrict__ aff2,
                                               double* __restrict__ acc3, int p0){
  __shared__ float xp[324];
  __shared__ float h1S[32*144];
  __shared__ float h2S[64*108];
  int bid=blockIdx.x, t=threadIdx.x;
  int p = p0 + (bid>>2), r0 = (bid&3)*4;
  for(int i=t;i<64*108;i+=256) h2S[i]=0.f;
  for(int i=t;i<324;i+=256) xp[i]=0.f;
  for(int i=t;i<32*144;i+=256) h1S[i]=0.f;
  __syncthreads();
  { int py=t>>4, px=t&15; xp[(py+1)*18 + px + 1] = x[(size_t)p*256+t]; }
  __syncthreads();
  {
    int rr=t>>5, cw=t&31, col=cw&15, half=cw>>4;
    int p1 = r0-1+rr;
    if(p1>=1 && p1<=16){
      float nb[9];
      #pragma unroll
      for(int j=0;j<9;j++) nb[j] = xp[(p1-1+j/3)*18 + col + (j%3)];
      for(int k=0;k<16;k++){
        int c = half*16+k;
        float a = wf[WS_B1+c];
        #pragma unroll
        for(int j=0;j<9;j++) a = fmaf(nb[j], wf[WS_W1+c*9+j], a);
        h1S[c*144 + rr*18 + col+1] = fmaxf((float)aff1[2*c]*a + (float)aff1[2*c+1], 0.f);
      }
    }
  }
  __syncthreads();
  {
    int col=t&15, g=t>>4;
    float a24[4][6];
    #pragma unroll
    for(int o=0;o<4;o++){
      float bv = wf[WS_B2+g*4+o];
      #pragma unroll
      for(int b2=0;b2<6;b2++) a24[o][b2] = bv;
    }
    #pragma unroll 1
    for(int ic=0;ic<32;ic++){
      const float* wrow = wf + WS_W2 + (g*4*32 + ic)*9;
      #pragma unroll
      for(int j=0;j<9;j++){
        float w4[4];
        #pragma unroll
        for(int o=0;o<4;o++) w4[o] = wrow[o*288 + j];
        int dy=j/3, dx=j%3;
        #pragma unroll
        for(int b2=0;b2<6;b2++){
          float m = h1S[ic*144 + (b2+dy)*18 + col + dx];
          #pragma unroll
          for(int o=0;o<4;o++) a24[o][b2] = fmaf(m, w4[o], a24[o][b2]);
        }
      }
    }
    #pragma unroll
    for(int b2=0;b2<6;b2++){
      int p2 = r0+b2;
      if(p2>=1 && p2<=16){
        #pragma unroll
        for(int o=0;o<4;o++){
          int c=g*4+o;
          h2S[c*108 + b2*18 + col+1] = fmaxf((float)aff2[2*c]*a24[o][b2] + (float)aff2[2*c+1], 0.f);
        }
      }
    }
  }
  __syncthreads();
  {
    int col = t & 15, og = t >> 4;
    float acc[8][4];
    #pragma unroll
    for(int o=0;o<8;o++){
      float bv = wf[WS_B3 + og*8 + o];
      #pragma unroll
      for(int r=0;r<4;r++) acc[o][r] = bv;
    }
    #pragma unroll 1
    for(int ic=0; ic<64; ++ic){
      float a[6][3];
      #pragma unroll
      for(int rr=0; rr<6; ++rr){
        #pragma unroll
        for(int dx=0; dx<3; ++dx) a[rr][dx] = h2S[ic*108 + rr*18 + col + dx];
      }
      const float* wrow = wf + WS_W3 + (og*8*64 + ic)*9;
      #pragma unroll
      for(int o=0;o<8;o++){
        #pragma unroll
        for(int j=0;j<9;j++){
          float w = wrow[o*576 + j];
          #pragma unroll
          for(int r=0;r<4;r++) acc[o][r] = fmaf(a[r + j/3][j%3], w, acc[o][r]);
        }
      }
    }
    #pragma unroll
    for(int o=0;o<8;o++){
      double s=0.0, q=0.0;
      #pragma unroll
      for(int r=0;r<4;r++){ double v=(double)acc[o][r]; s+=v; q+=v*v; }
      #pragma unroll
      for(int off=8; off; off>>=1){ s += __shfl_down(s, off, 16); q += __shfl_down(q, off, 16); }
      if(col==0){
        int c = og*8+o;
        atomicAdd(&acc3[(bid&63)*256 + c*2 + 0], s);
        atomicAdd(&acc3[(bid&63)*256 + c*2 + 1], q);
      }
    }
  }
}

// ========= FALLBACK recompute conv3 feat (f64), patches p0.. =========
__global__ __launch_bounds__(256) void k_p34(const float* __restrict__ x, const float* __restrict__ wf,
                                             const double* __restrict__ aff1, const double* __restrict__ aff2,
                                             const double* __restrict__ aff3, double* __restrict__ outp,
                                             int p0){
  __shared__ float xp[324];
  __shared__ float h1S[32*144];
  __shared__ float h2S[64*108];
  int bid=blockIdx.x, t=threadIdx.x;
  int p = p0 + (bid>>2), r0 = (bid&3)*4;
  for(int i=t;i<64*108;i+=256) h2S[i]=0.f;
  for(int i=t;i<324;i+=256) xp[i]=0.f;
  for(int i=t;i<32*144;i+=256) h1S[i]=0.f;
  __syncthreads();
  { int py=t>>4, px=t&15; xp[(py+1)*18 + px + 1] = x[(size_t)p*256+t]; }
  __syncthreads();
  {
    int rr=t>>5, cw=t&31, col=cw&15, half=cw>>4;
    int p1 = r0-1+rr;
    if(p1>=1 && p1<=16){
      double nb[9];
      #pragma unroll
      for(int j=0;j<9;j++) nb[j] = (double)xp[(p1-1+j/3)*18 + col + (j%3)];
      for(int k=0;k<16;k++){
        int c = half*16+k;
        double a = (double)wf[WS_B1+c];
        #pragma unroll
        for(int j=0;j<9;j++) a = fma(nb[j], (double)wf[WS_W1+c*9+j], a);
        h1S[c*144 + rr*18 + col+1] = (float)fmax(aff1[2*c]*a + aff1[2*c+1], 0.0);
      }
    }
  }
  __syncthreads();
  {
    int col=t&15, g=t>>4;
    double a24[4][6];
    #pragma unroll
    for(int o=0;o<4;o++){
      double bv = (double)wf[WS_B2+g*4+o];
      #pragma unroll
      for(int b2=0;b2<6;b2++) a24[o][b2] = bv;
    }
    #pragma unroll 1
    for(int ic=0;ic<32;ic++){
      const float* wrow = wf + WS_W2 + (g*4*32 + ic)*9;
      #pragma unroll
      for(int j=0;j<9;j++){
        double w4[4];
        #pragma unroll
        for(int o=0;o<4;o++) w4[o] = (double)wrow[o*288 + j];
        int dy=j/3, dx=j%3;
        #pragma unroll
        for(int b2=0;b2<6;b2++){
          double m = (double)h1S[ic*144 + (b2+dy)*18 + col + dx];
          #pragma unroll
          for(int o=0;o<4;o++) a24[o][b2] = fma(m, w4[o], a24[o][b2]);
        }
      }
    }
    #pragma unroll
    for(int b2=0;b2<6;b2++){
      int p2 = r0+b2;
      if(p2>=1 && p2<=16){
        #pragma unroll
        for(int o=0;o<4;o++){
          int c=g*4+o;
          h2S[c*108 + b2*18 + col+1] = (float)fmax(aff2[2*c]*a24[o][b2] + aff2[2*c+1], 0.0);
        }
      }
    }
  }
  __syncthreads();
  {
    int col = t & 15, og = t >> 4;
    double acc[8][4];
    #pragma unroll
    for(int o=0;o<8;o++){
      double bv = (double)wf[WS_B3 + og*8 + o];
      #pragma unroll
      for(int r=0;r<4;r++) acc[o][r] = bv;
    }
    #pragma unroll 1
    for(int ic=0; ic<64; ++ic){
      double a[6][3];
      #pragma unroll
      for(int rr=0; rr<6; ++rr){
        #pragma unroll
        for(int dx=0; dx<3; ++dx) a[rr][dx] = (double)h2S[ic*108 + rr*18 + col + dx];
      }
      const float* wrow = wf + WS_W3 + (og*8*64 + ic)*9;
      #pragma unroll
      for(int o=0;o<8;o++){
        #pragma unroll
        for(int j=0;j<9;j++){
          double w = (double)wrow[o*576 + j];
          #pragma unroll
          for(int r=0;r<4;r++) acc[o][r] = fma(a[r + j/3][j%3], w, acc[o][r]);
        }
      }
    }
    #pragma unroll
    for(int o=0;o<8;o++){
      int c = og*8+o;
      double sc=aff3[2*c], sh=aff3[2*c+1];
      double s = 0.0;
      #pragma unroll
      for(int r=0;r<4;r++) s += fmax(fma(sc, acc[o][r], sh), 0.0);
      #pragma unroll
      for(int off=8; off; off>>=1) s += __shfl_down(s, off, 16);
      if(col==0) atomicAdd(&outp[(size_t)p*128 + c], s);
    }
  }
}

// ---------------- LN + relu on [4][512] f64 LDS buffer ----------------
__device__ __forceinline__ void ln_relu4(double* buf, const float* __restrict__ g, const float* __restrict__ b,
                                         double* lnm, double* lnr, int t){
  int r=t>>6, j=t&63;
  double s=0.0, q=0.0;
  for(int k=j;k<512;k+=64){ double v=buf[r*512+k]; s+=v; q+=v*v; }
  #pragma unroll
  for(int off=32;off;off>>=1){ s+=__shfl_down(s,off); q+=__shfl_down(q,off); }
  if(j==0){
    double m = s*(1.0/512.0);
    double v = q*(1.0/512.0) - m*m;
    lnm[r]=m; lnr[r]=1.0/sqrt(v + 1e-5);
  }
  __syncthreads();
  for(int i=t;i<2048;i+=256){
    int r2=i>>9, k=i&511;
    double v=(buf[i]-lnm[r2])*lnr[r2]*(double)g[k]+(double)b[k];
    buf[i]=fmax(v,0.0);
  }
  __syncthreads();
}

// ---------------- MLP head (f64): feat -> assignment f32 (4 rows/block; R12 version) ----------------
__global__ __launch_bounds__(256) void k_mlp(const float* __restrict__ wf, const double* __restrict__ feat,
                                             float* __restrict__ assign_out){
  int r0 = blockIdx.x*4, t = threadIdx.x;
  __shared__ double f0[4*128];
  __shared__ double f1[4*256];
  __shared__ double f2[4*512];
  __shared__ double f3[4*512];
  __shared__ double lnm[4], lnr[4];
  __shared__ double lg[4][8];

  for(int i=t;i<512;i+=256) f0[i] = feat[(size_t)r0*128 + i] * (1.0/256.0);
  __syncthreads();
  {
    double acc[4];
    double bv = (double)wf[WS_FCB + t];
    #pragma unroll
    for(int r=0;r<4;r++) acc[r]=bv;
    for(int k=0;k<128;k++){
      double wv = (double)wf[WS_FCW + t*128 + k];
      #pragma unroll
      for(int r=0;r<4;r++) acc[r]=fma(wv, f0[r*128+k], acc[r]);
    }
    #pragma unroll
    for(int r=0;r<4;r++) f1[r*256+t]=acc[r];
  }
  __syncthreads();
  for(int half=0;half<2;half++){
    int i=t+(half<<8);
    double acc[4];
    double bv=(double)wf[WS_G1B+i];
    #pragma unroll
    for(int r=0;r<4;r++) acc[r]=bv;
    for(int k=0;k<256;k++){
      double wv=(double)wf[WS_G1W + i*256 + k];
      #pragma unroll
      for(int r=0;r<4;r++) acc[r]=fma(wv, f1[r*256+k], acc[r]);
    }
    #pragma unroll
    for(int r=0;r<4;r++) f2[r*512+i]=acc[r];
  }
  __syncthreads();
  ln_relu4(f2, wf+WS_L1G, wf+WS_L1B, lnm, lnr, t);
  for(int half=0;half<2;half++){
    int i=t+(half<<8);
    double acc[4];
    double bv=(double)wf[WS_G2B+i];
    #pragma unroll
    for(int r=0;r<4;r++) acc[r]=bv;
    for(int k=0;k<512;k++){
      double wv=(double)wf[WS_G2W + i*512 + k];
      #pragma unroll
      for(int r=0;r<4;r++) acc[r]=fma(wv, f2[r*512+k], acc[r]);
    }
    #pragma unroll
    for(int r=0;r<4;r++) f3[r*512+i]=acc[r];
  }
  __syncthreads();
  ln_relu4(f3, wf+WS_L2G, wf+WS_L2B, lnm, lnr, t);
  {
    int r=t>>6, j=t&63;
    double pl[8];
    #pragma unroll
    for(int g=0;g<8;g++){
      double s=0.0;
      for(int k=j;k<512;k+=64) s = fma(f3[r*512+k], (double)wf[WS_G3W + g*512 + k], s);
      pl[g]=s;
    }
    #pragma unroll
    for(int off=32;off;off>>=1){
      #pragma unroll
      for(int g=0;g<8;g++) pl[g] += __shfl_down(pl[g], off);
    }
    if(j==0){
      #pragma unroll
      for(int g=0;g<8;g++) lg[r][g] = (pl[g] + (double)wf[WS_G3B+g]) * 2.0; // /TEMP
    }
  }
  __syncthreads();
  if(t<4){
    double m=-1e300;
    #pragma unroll
    for(int g=0;g<8;g++) m = fmax(m, lg[t][g]);
    double e[8], s=0.0;
    #pragma unroll
    for(int g=0;g<8;g++){ e[g]=exp(lg[t][g]-m); s+=e[g]; }
    double inv = 1.0/s;
    int row = r0 + t;
    #pragma unroll
    for(int g=0;g<8;g++) assign_out[row*8+g] = (float)(e[g]*inv);
  }
}

// ---------------- top-32 per (b,g) + gather*scale ----------------
__global__ __launch_bounds__(256) void k_topk(const float* __restrict__ assign, const float* __restrict__ x,
                                              float* __restrict__ out){
  int b = blockIdx.x >> 3, g = blockIdx.x & 7, t = threadIdx.x;
  __shared__ float v[256];
  __shared__ int   id[256];
  v[t] = assign[(b*256+t)*8 + g];
  id[t] = t;
  __syncthreads();
  for(int k=2;k<=256;k<<=1){
    for(int j=k>>1;j>0;j>>=1){
      int ixj = t ^ j;
      if(ixj > t){
        float va=v[t], vb=v[ixj];
        int ia=id[t], ib=id[ixj];
        bool aBefore = (va > vb) || (va == vb && ia < ib);
        bool up = ((t & k) == 0);
        if(up != aBefore){ v[t]=vb; v[ixj]=va; id[t]=ib; id[ixj]=ia; }
      }
      __syncthreads();
    }
  }
  __shared__ float tv[32];
  __shared__ int   ti[32];
  if(t<32){ tv[t]=v[t]; ti[t]=id[t]; }
  __syncthreads();
  const float* xb = x + (size_t)b*65536;
  float* ob = out + (size_t)(b*8+g)*8192;
  for(int i=t;i<8192;i+=256){
    int k=i>>8, pix=i&255;
    ob[i] = tv[k] * xb[ti[k]*256 + pix];
  }
}

// ---------------- launcher ----------------
extern "C" void kernel_launch(void* const* d_in, const int* in_sizes, int n_in,
                              void* d_out, int out_size, void* d_ws, size_t ws_size,
                              hipStream_t stream){
  const float* x = (const float*)d_in[0];
  float*  ws  = (float*)d_ws;
  double* dws = (double*)d_ws;
  float* out = (float*)d_out;
  float* assign_out = out + 1048576;
  float* z2 = (float*)((char*)d_ws + Z2_OFF_B);

  int nS = 0;
  if(ws_size > Z2_OFF_B + 65536){
    unsigned long long avail = (unsigned long long)ws_size - Z2_OFF_B;
    unsigned long long n = avail / 65536ull;
    nS = (n > 4096ull) ? 4096 : (int)n;
  }
  int nR = 4096 - nS;

  const float* g1=(const float*)d_in[3];  const float* b1=(const float*)d_in[4];
  const float* g2=(const float*)d_in[7];  const float* b2=(const float*)d_in[8];
  const float* g3=(const float*)d_in[11]; const float* b3=(const float*)d_in[12];

  WP wp;
  const int map[18] = {1,2,5,6,9,10,13,14,15,16,17,18,19,20,21,22,23,24};
  for(int i=0;i<18;i++) wp.p[i] = (const float*)d_in[map[i]];

  k_zero <<<2162, 256, 0, stream>>>(dws + D_ACC1);
  k_cvt  <<<dim3(1024,18), 256, 0, stream>>>(wp, ws);
  k_p1   <<<4096, 256, 0, stream>>>(x, ws, dws+D_ACC1);
  k_fin  <<<32, 64, 0, stream>>>(dws+D_ACC1, 32, g1, b1, dws+D_AFF1);
  k_p2   <<<4096, 256, 0, stream>>>(x, ws, dws+D_AFF1, dws+D_ACC2, z2, nS);
  k_fin  <<<64, 64, 0, stream>>>(dws+D_ACC2, 64, g2, b2, dws+D_AFF2);
  if(nS > 0) k_cs   <<<3*nS, 256, 0, stream>>>(ws, dws+D_AFF2, dws+D_ACC3, z2);
  if(nR > 0) k_stat3<<<4*nR, 256, 0, stream>>>(x, ws, dws+D_AFF1, dws+D_AFF2, dws+D_ACC3, nS);
  k_fin  <<<128, 64, 0, stream>>>(dws+D_ACC3, 128, g3, b3, dws+D_AFF3);
  if(nS > 0) k_cf  <<<3*nS, 256, 0, stream>>>(ws, dws+D_AFF2, dws+D_AFF3, dws+D_FEAT, z2);
  if(nR > 0) k_p34 <<<4*nR, 256, 0, stream>>>(x, ws, dws+D_AFF1, dws+D_AFF2, dws+D_AFF3, dws+D_FEAT, nS);
  k_mlp  <<<1024, 256, 0, stream>>>(ws, dws+D_FEAT, assign_out);
  k_topk <<<128, 256, 0, stream>>>(assign_out, x, out);
}

// Round 15
// 4936.605 us; speedup vs baseline: 1.5043x; 1.1934x over previous
//
#include <hip/hip_runtime.h>

// Inputs f32, outputs f32. Precision map (all hardware-validated):
//   - BN stats passes (k_p1, conv2/conv3 stats): f32 conv + f64 accumulate —
//     1M-pixel averages wash out rounding (R12/R14, absmax at floor).
//   - Value chain conv: f32 (conv3 f32 in R14 passed at floor; z2 is stored
//     f32 anyway so f32 conv2 adds noise at the already-survived scale).
//   - BN affine / feat accumulate / MLP / softmax: f64 (R4: cheap f32 here
//     caused top-k rank swaps).
// Conv weights f32 (f64 weights thrash L1: R7/R9). z2 staged f32 (R11);
// ws_size in [275,277) MB so z3 staging impossible. R15: 8-row strips (zero
// waste), 8 oc/thread (FMA:aux 5.6), f32 k_p1/k_p2.

// ---- f32 weight block (float offsets into ws) ----
#define WS_W1   0
#define WS_B1   288
#define WS_W2   320
#define WS_B2   18752
#define WS_W3   18816
#define WS_B3   92544
#define WS_FCW  92672
#define WS_FCB  125440
#define WS_G1W  125696
#define WS_G1B  256768
#define WS_L1G  257280
#define WS_L1B  257792
#define WS_G2W  258304
#define WS_G2B  520448
#define WS_L2G  520960
#define WS_L2B  521472
#define WS_G3W  521984
#define WS_G3B  526080
// ---- f64 region (double offsets into ws) ----
#define D_ACC1  263044
#define D_ACC2  (D_ACC1 + 4096)
#define D_ACC3  (D_ACC2 + 8192)
#define D_FEAT  (D_ACC3 + 16384)
#define D_AFF1  (D_FEAT + 524288)
#define D_AFF2  (D_AFF1 + 64)
#define D_AFF3  (D_AFF2 + 128)
#define D_ZN    553408        // doubles zeroed from D_ACC1; region ends at byte 6,531,616
// ---- z2 staging: first 512-aligned byte AFTER the f64 region ----
#define Z2_OFF_B 6532096ull

// ---------------- zero f64 accumulators ----------------
__global__ __launch_bounds__(256) void k_zero(double* __restrict__ dst){
  int i = blockIdx.x*256 + threadIdx.x;
  if(i < D_ZN) dst[i] = 0.0;
}

// ---------------- weight gather-copy (f32) ----------------
struct WP { const float* p[18]; };

__global__ __launch_bounds__(256) void k_cvt(WP wp, float* __restrict__ dst){
  const int segn[18] = {288,32,18432,64,73728,128,32768,256,131072,512,512,512,262144,512,512,512,4096,8};
  const int sego[18] = {WS_W1,WS_B1,WS_W2,WS_B2,WS_W3,WS_B3,WS_FCW,WS_FCB,WS_G1W,WS_G1B,
                        WS_L1G,WS_L1B,WS_G2W,WS_G2B,WS_L2G,WS_L2B,WS_G3W,WS_G3B};
  int s = blockIdx.y;
  int i = blockIdx.x*256 + threadIdx.x;
  if(i < segn[s]) dst[sego[s]+i] = wp.p[s][i];
}

// ---------------- finalize BN stats ----------------
__global__ __launch_bounds__(64) void k_fin(const double* __restrict__ acc, int C,
                                            const float* __restrict__ gam, const float* __restrict__ bet,
                                            double* __restrict__ aff){
  int c = blockIdx.x, t = threadIdx.x;
  double s = acc[t*2*C + c*2];
  double q = acc[t*2*C + c*2 + 1];
  #pragma unroll
  for(int off=32;off;off>>=1){ s += __shfl_down(s,off); q += __shfl_down(q,off); }
  if(t==0){
    double m = s*(1.0/1048576.0);
    double v = q*(1.0/1048576.0) - m*m;
    double sc = (double)gam[c] / sqrt(v + 1e-5);
    aff[2*c]   = sc;
    aff[2*c+1] = (double)bet[c] - m*sc;
  }
}

// ---------------- pass 1: conv1 raw stats (f32 conv, f64 accumulate) ----------------
__global__ __launch_bounds__(256) void k_p1(const float* __restrict__ x, const float* __restrict__ wf,
                                            double* __restrict__ acc1){
  __shared__ float xp[324];
  __shared__ double red[4][32][2];
  int p = blockIdx.x, t = threadIdx.x;
  for(int i=t;i<324;i+=256) xp[i]=0.f;
  __syncthreads();
  int py=t>>4, px=t&15;
  xp[(py+1)*18 + px + 1] = x[(size_t)p*256+t];
  __syncthreads();
  float nb[9];
  #pragma unroll
  for(int j=0;j<9;j++) nb[j] = xp[(py+j/3)*18 + px + (j%3)];
  int wave=t>>6, lane=t&63;
  for(int c=0;c<32;c++){
    float a = wf[WS_B1+c];
    #pragma unroll
    for(int j=0;j<9;j++) a = fmaf(nb[j], wf[WS_W1+c*9+j], a);
    double av=(double)a;
    double s=av, q=av*av;
    #pragma unroll
    for(int off=32;off;off>>=1){ s+=__shfl_down(s,off); q+=__shfl_down(q,off); }
    if(lane==0){ red[wave][c][0]=s; red[wave][c][1]=q; }
  }
  __syncthreads();
  if(t<64){
    int c=t>>1, st=t&1;
    double v = red[0][c][st]+red[1][c][st]+red[2][c][st]+red[3][c][st];
    atomicAdd(&acc1[(p&63)*64 + c*2 + st], v);
  }
}

// ---------------- pass 2 (f32): conv1 -> bn1relu -> conv2 stats (+ z2 store) ----------------
__global__ __launch_bounds__(256) void k_p2(const float* __restrict__ x, const float* __restrict__ wf,
                                            const double* __restrict__ aff1, double* __restrict__ acc2,
                                            float* __restrict__ z2, int nS){
  __shared__ float xp[324];
  __shared__ float h1f[32*324];
  int p=blockIdx.x, t=threadIdx.x;
  for(int i=t;i<324;i+=256) xp[i]=0.f;
  for(int i=t;i<32*324;i+=256) h1f[i]=0.f;
  __syncthreads();
  int py=t>>4, px=t&15;
  xp[(py+1)*18 + px + 1] = x[(size_t)p*256+t];
  __syncthreads();
  {
    float nb[9];
    #pragma unroll
    for(int j=0;j<9;j++) nb[j] = xp[(py+j/3)*18 + px + (j%3)];
    for(int c=0;c<32;c++){
      float a = wf[WS_B1+c];
      #pragma unroll
      for(int j=0;j<9;j++) a = fmaf(nb[j], wf[WS_W1+c*9+j], a);
      h1f[c*324 + (py+1)*18 + (px+1)] = fmaxf(fmaf((float)aff1[2*c], a, (float)aff1[2*c+1]), 0.f);
    }
  }
  __syncthreads();
  int col=t&15, og=t>>4;
  bool wr = (p < nS);
  double sT[4]={0,0,0,0}, qT[4]={0,0,0,0};
  #pragma unroll 1
  for(int half=0; half<2; ++half){
    float acc[4][8];
    #pragma unroll
    for(int o=0;o<4;o++){
      float bv = wf[WS_B2 + og*4 + o];
      #pragma unroll
      for(int r=0;r<8;r++) acc[o][r]=bv;
    }
    #pragma unroll 1
    for(int ic=0; ic<32; ++ic){
      const float* wrow = wf + WS_W2 + (og*4*32 + ic)*9;
      #pragma unroll
      for(int j=0;j<9;j++){
        float w4[4];
        #pragma unroll
        for(int o=0;o<4;o++) w4[o] = wrow[o*288 + j];
        int dy=j/3, dx=j%3;
        #pragma unroll
        for(int r=0;r<8;r++){
          float m = h1f[ic*324 + (half*8 + r + dy)*18 + col + dx];
          #pragma unroll
          for(int o=0;o<4;o++) acc[o][r] = fmaf(m, w4[o], acc[o][r]);
        }
      }
    }
    #pragma unroll
    for(int o=0;o<4;o++){
      #pragma unroll
      for(int r=0;r<8;r++){ double v=(double)acc[o][r]; sT[o]+=v; qT[o]+=v*v; }
      if(wr){
        int c = og*4+o;
        #pragma unroll
        for(int r=0;r<8;r++) z2[((size_t)p*64+c)*256 + (half*8+r)*16 + col] = acc[o][r];
      }
    }
  }
  #pragma unroll
  for(int o=0;o<4;o++){
    double s=sT[o], q=qT[o];
    #pragma unroll
    for(int off=8;off;off>>=1){ s+=__shfl_down(s,off,16); q+=__shfl_down(q,off,16); }
    if(col==0){
      int c = og*4+o;
      atomicAdd(&acc2[(p&63)*128 + c*2 + 0], s);
      atomicAdd(&acc2[(p&63)*128 + c*2 + 1], q);
    }
  }
}

// ========= STAGED conv3 stats (f32): 8-row strips (2/patch), 8 oc/thread =========
__global__ __launch_bounds__(256) void k_cs(const float* __restrict__ wf, const double* __restrict__ aff2,
                                            double* __restrict__ acc3, const float* __restrict__ z2){
  __shared__ float h2S[64*180];   // [ch][10 input rows][18 cols]
  int bid=blockIdx.x, t=threadIdx.x;
  int p = bid>>1, r0 = (bid&1)*8;
  for(int i=t;i<64*180;i+=256) h2S[i]=0.f;
  __syncthreads();
  for(int i=t;i<10240;i+=256){      // 64 ch x 10 rows x 16 cols
    int ch = i/160, rem = i - ch*160;
    int row = rem>>4, c2 = rem&15;
    int gr = r0 - 1 + row;
    if(gr>=0 && gr<16){
      float zv = z2[((size_t)p*64+ch)*256 + gr*16 + c2];
      h2S[ch*180 + row*18 + c2+1] = fmaxf(fmaf((float)aff2[2*ch], zv, (float)aff2[2*ch+1]), 0.f);
    }
  }
  __syncthreads();
  int col=t&15, og=t>>4;            // og 0..15, 8 oc each -> all 128 oc
  float acc[8][8];                  // [oc][row]
  #pragma unroll
  for(int o=0;o<8;o++){
    float bv = wf[WS_B3 + og*8 + o];
    #pragma unroll
    for(int r=0;r<8;r++) acc[o][r]=bv;
  }
  #pragma unroll 1
  for(int ic=0; ic<64; ++ic){
    float a[10][3];
    #pragma unroll
    for(int lr=0; lr<10; ++lr){
      #pragma unroll
      for(int dx=0; dx<3; ++dx) a[lr][dx] = h2S[ic*180 + lr*18 + col + dx];
    }
    const float* wrow = wf + WS_W3 + ((size_t)(og*8)*64 + ic)*9;
    #pragma unroll
    for(int o=0;o<8;o++){
      #pragma unroll
      for(int j=0;j<9;j++){
        float w = wrow[o*576 + j];
        #pragma unroll
        for(int r=0;r<8;r++) acc[o][r] = fmaf(a[r + j/3][j%3], w, acc[o][r]);
      }
    }
  }
  #pragma unroll
  for(int o=0;o<8;o++){
    double s=0.0, q=0.0;
    #pragma unroll
    for(int r=0;r<8;r++){ double v=(double)acc[o][r]; s+=v; q+=v*v; }
    #pragma unroll
    for(int off=8; off; off>>=1){ s += __shfl_down(s, off, 16); q += __shfl_down(q, off, 16); }
    if(col==0){
      int c = og*8+o;
      atomicAdd(&acc3[(bid&63)*256 + c*2 + 0], s);
      atomicAdd(&acc3[(bid&63)*256 + c*2 + 1], q);
    }
  }
}

// ========= STAGED conv3 feat (f32 conv, f64 accumulate): 8-row strips =========
__global__ __launch_bounds__(256) void k_cf(const float* __restrict__ wf, const double* __restrict__ aff2,
                                            const double* __restrict__ aff3, double* __restrict__ feat,
                                            const float* __restrict__ z2){
  __shared__ float h2S[64*180];
  int bid=blockIdx.x, t=threadIdx.x;
  int p = bid>>1, r0 = (bid&1)*8;
  for(int i=t;i<64*180;i+=256) h2S[i]=0.f;
  __syncthreads();
  for(int i=t;i<10240;i+=256){
    int ch = i/160, rem = i - ch*160;
    int row = rem>>4, c2 = rem&15;
    int gr = r0 - 1 + row;
    if(gr>=0 && gr<16){
      float zv = z2[((size_t)p*64+ch)*256 + gr*16 + c2];
      h2S[ch*180 + row*18 + c2+1] = fmaxf(fmaf((float)aff2[2*ch], zv, (float)aff2[2*ch+1]), 0.f);
    }
  }
  __syncthreads();
  int col=t&15, og=t>>4;
  float acc[8][8];
  #pragma unroll
  for(int o=0;o<8;o++){
    float bv = wf[WS_B3 + og*8 + o];
    #pragma unroll
    for(int r=0;r<8;r++) acc[o][r]=bv;
  }
  #pragma unroll 1
  for(int ic=0; ic<64; ++ic){
    float a[10][3];
    #pragma unroll
    for(int lr=0; lr<10; ++lr){
      #pragma unroll
      for(int dx=0; dx<3; ++dx) a[lr][dx] = h2S[ic*180 + lr*18 + col + dx];
    }
    const float* wrow = wf + WS_W3 + ((size_t)(og*8)*64 + ic)*9;
    #pragma unroll
    for(int o=0;o<8;o++){
      #pragma unroll
      for(int j=0;j<9;j++){
        float w = wrow[o*576 + j];
        #pragma unroll
        for(int r=0;r<8;r++) acc[o][r] = fmaf(a[r + j/3][j%3], w, acc[o][r]);
      }
    }
  }
  #pragma unroll
  for(int o=0;o<8;o++){
    int c = og*8+o;
    float sc=(float)aff3[2*c], sh=(float)aff3[2*c+1];
    double sv = 0.0;
    #pragma unroll
    for(int r=0;r<8;r++) sv += (double)fmaxf(fmaf(sc, acc[o][r], sh), 0.f);
    #pragma unroll
    for(int off=8; off; off>>=1) sv += __shfl_down(sv, off, 16);
    if(col==0) atomicAdd(&feat[(size_t)p*128 + c], sv);
  }
}

// ========= FALLBACK recompute conv3 stats (f32), patches p0.. =========
__global__ __launch_bounds__(256) void k_stat3(const float* __restrict__ x, const float* __restrict__ wf,
                                               const double* __restrict__ aff1, const double* __restrict__ aff2,
                                               double* __restrict__ acc3, int p0){
  __shared__ float xp[324];
  __shared__ float h1S[32*144];
  __shared__ float h2S[64*108];
  int bid=blockIdx.x, t=threadIdx.x;
  int p = p0 + (bid>>2), r0 = (bid&3)*4;
  for(int i=t;i<64*108;i+=256) h2S[i]=0.f;
  for(int i=t;i<324;i+=256) xp[i]=0.f;
  for(int i=t;i<32*144;i+=256) h1S[i]=0.f;
  __syncthreads();
  { int py=t>>4, px=t&15; xp[(py+1)*18 + px + 1] = x[(size_t)p*256+t]; }
  __syncthreads();
  {
    int rr=t>>5, cw=t&31, col=cw&15, half=cw>>4;
    int p1 = r0-1+rr;
    if(p1>=1 && p1<=16){
      float nb[9];
      #pragma unroll
      for(int j=0;j<9;j++) nb[j] = xp[(p1-1+j/3)*18 + col + (j%3)];
      for(int k=0;k<16;k++){
        int c = half*16+k;
        float a = wf[WS_B1+c];
        #pragma unroll
        for(int j=0;j<9;j++) a = fmaf(nb[j], wf[WS_W1+c*9+j], a);
        h1S[c*144 + rr*18 + col+1] = fmaxf((float)aff1[2*c]*a + (float)aff1[2*c+1], 0.f);
      }
    }
  }
  __syncthreads();
  {
    int col=t&15, g=t>>4;
    float a24[4][6];
    #pragma unroll
    for(int o=0;o<4;o++){
      float bv = wf[WS_B2+g*4+o];
      #pragma unroll
      for(int b2=0;b2<6;b2++) a24[o][b2] = bv;
    }
    #pragma unroll 1
    for(int ic=0;ic<32;ic++){
      const float* wrow = wf + WS_W2 + (g*4*32 + ic)*9;
      #pragma unroll
      for(int j=0;j<9;j++){
        float w4[4];
        #pragma unroll
        for(int o=0;o<4;o++) w4[o] = wrow[o*288 + j];
        int dy=j/3, dx=j%3;
        #pragma unroll
        for(int b2=0;b2<6;b2++){
          float m = h1S[ic*144 + (b2+dy)*18 + col + dx];
          #pragma unroll
          for(int o=0;o<4;o++) a24[o][b2] = fmaf(m, w4[o], a24[o][b2]);
        }
      }
    }
    #pragma unroll
    for(int b2=0;b2<6;b2++){
      int p2 = r0+b2;
      if(p2>=1 && p2<=16){
        #pragma unroll
        for(int o=0;o<4;o++){
          int c=g*4+o;
          h2S[c*108 + b2*18 + col+1] = fmaxf((float)aff2[2*c]*a24[o][b2] + (float)aff2[2*c+1], 0.f);
        }
      }
    }
  }
  __syncthreads();
  {
    int col = t & 15, og = t >> 4;
    float acc[8][4];
    #pragma unroll
    for(int o=0;o<8;o++){
      float bv = wf[WS_B3 + og*8 + o];
      #pragma unroll
      for(int r=0;r<4;r++) acc[o][r] = bv;
    }
    #pragma unroll 1
    for(int ic=0; ic<64; ++ic){
      float a[6][3];
      #pragma unroll
      for(int rr=0; rr<6; ++rr){
        #pragma unroll
        for(int dx=0; dx<3; ++dx) a[rr][dx] = h2S[ic*108 + rr*18 + col + dx];
      }
      const float* wrow = wf + WS_W3 + (og*8*64 + ic)*9;
      #pragma unroll
      for(int o=0;o<8;o++){
        #pragma unroll
        for(int j=0;j<9;j++){
          float w = wrow[o*576 + j];
          #pragma unroll
          for(int r=0;r<4;r++) acc[o][r] = fmaf(a[r + j/3][j%3], w, acc[o][r]);
        }
      }
    }
    #pragma unroll
    for(int o=0;o<8;o++){
      double s=0.0, q=0.0;
      #pragma unroll
      for(int r=0;r<4;r++){ double v=(double)acc[o][r]; s+=v; q+=v*v; }
      #pragma unroll
      for(int off=8; off; off>>=1){ s += __shfl_down(s, off, 16); q += __shfl_down(q, off, 16); }
      if(col==0){
        int c = og*8+o;
        atomicAdd(&acc3[(bid&63)*256 + c*2 + 0], s);
        atomicAdd(&acc3[(bid&63)*256 + c*2 + 1], q);
      }
    }
  }
}

// ========= FALLBACK recompute conv3 feat (f32 conv, f64 accumulate), patches p0.. =========
__global__ __launch_bounds__(256) void k_p34(const float* __restrict__ x, const float* __restrict__ wf,
                                             const double* __restrict__ aff1, const double* __restrict__ aff2,
                                             const double* __restrict__ aff3, double* __restrict__ outp,
                                             int p0){
  __shared__ float xp[324];
  __shared__ float h1S[32*144];
  __shared__ float h2S[64*108];
  int bid=blockIdx.x, t=threadIdx.x;
  int p = p0 + (bid>>2), r0 = (bid&3)*4;
  for(int i=t;i<64*108;i+=256) h2S[i]=0.f;
  for(int i=t;i<324;i+=256) xp[i]=0.f;
  for(int i=t;i<32*144;i+=256) h1S[i]=0.f;
  __syncthreads();
  { int py=t>>4, px=t&15; xp[(py+1)*18 + px + 1] = x[(size_t)p*256+t]; }
  __syncthreads();
  {
    int rr=t>>5, cw=t&31, col=cw&15, half=cw>>4;
    int p1 = r0-1+rr;
    if(p1>=1 && p1<=16){
      float nb[9];
      #pragma unroll
      for(int j=0;j<9;j++) nb[j] = xp[(p1-1+j/3)*18 + col + (j%3)];
      for(int k=0;k<16;k++){
        int c = half*16+k;
        float a = wf[WS_B1+c];
        #pragma unroll
        for(int j=0;j<9;j++) a = fmaf(nb[j], wf[WS_W1+c*9+j], a);
        h1S[c*144 + rr*18 + col+1] = fmaxf((float)aff1[2*c]*a + (float)aff1[2*c+1], 0.f);
      }
    }
  }
  __syncthreads();
  {
    int col=t&15, g=t>>4;
    float a24[4][6];
    #pragma unroll
    for(int o=0;o<4;o++){
      float bv = wf[WS_B2+g*4+o];
      #pragma unroll
      for(int b2=0;b2<6;b2++) a24[o][b2] = bv;
    }
    #pragma unroll 1
    for(int ic=0;ic<32;ic++){
      const float* wrow = wf + WS_W2 + (g*4*32 + ic)*9;
      #pragma unroll
      for(int j=0;j<9;j++){
        float w4[4];
        #pragma unroll
        for(int o=0;o<4;o++) w4[o] = wrow[o*288 + j];
        int dy=j/3, dx=j%3;
        #pragma unroll
        for(int b2=0;b2<6;b2++){
          float m = h1S[ic*144 + (b2+dy)*18 + col + dx];
          #pragma unroll
          for(int o=0;o<4;o++) a24[o][b2] = fmaf(m, w4[o], a24[o][b2]);
        }
      }
    }
    #pragma unroll
    for(int b2=0;b2<6;b2++){
      int p2 = r0+b2;
      if(p2>=1 && p2<=16){
        #pragma unroll
        for(int o=0;o<4;o++){
          int c=g*4+o;
          h2S[c*108 + b2*18 + col+1] = fmaxf((float)aff2[2*c]*a24[o][b2] + (float)aff2[2*c+1], 0.f);
        }
      }
    }
  }
  __syncthreads();
  {
    int col = t & 15, og = t >> 4;
    float acc[8][4];
    #pragma unroll
    for(int o=0;o<8;o++){
      float bv = wf[WS_B3 + og*8 + o];
      #pragma unroll
      for(int r=0;r<4;r++) acc[o][r] = bv;
    }
    #pragma unroll 1
    for(int ic=0; ic<64; ++ic){
      float a[6][3];
      #pragma unroll
      for(int rr=0; rr<6; ++rr){
        #pragma unroll
        for(int dx=0; dx<3; ++dx) a[rr][dx] = h2S[ic*108 + rr*18 + col + dx];
      }
      const float* wrow = wf + WS_W3 + (og*8*64 + ic)*9;
      #pragma unroll
      for(int o=0;o<8;o++){
        #pragma unroll
        for(int j=0;j<9;j++){
          float w = wrow[o*576 + j];
          #pragma unroll
          for(int r=0;r<4;r++) acc[o][r] = fmaf(a[r + j/3][j%3], w, acc[o][r]);
        }
      }
    }
    #pragma unroll
    for(int o=0;o<8;o++){
      int c = og*8+o;
      float sc=(float)aff3[2*c], sh=(float)aff3[2*c+1];
      double s = 0.0;
      #pragma unroll
      for(int r=0;r<4;r++) s += (double)fmaxf(fmaf(sc, acc[o][r], sh), 0.f);
      #pragma unroll
      for(int off=8; off; off>>=1) s += __shfl_down(s, off, 16);
      if(col==0) atomicAdd(&outp[(size_t)p*128 + c], s);
    }
  }
}

// ---------------- LN + relu on [4][512] f64 LDS buffer ----------------
__device__ __forceinline__ void ln_relu4(double* buf, const float* __restrict__ g, const float* __restrict__ b,
                                         double* lnm, double* lnr, int t){
  int r=t>>6, j=t&63;
  double s=0.0, q=0.0;
  for(int k=j;k<512;k+=64){ double v=buf[r*512+k]; s+=v; q+=v*v; }
  #pragma unroll
  for(int off=32;off;off>>=1){ s+=__shfl_down(s,off); q+=__shfl_down(q,off); }
  if(j==0){
    double m = s*(1.0/512.0);
    double v = q*(1.0/512.0) - m*m;
    lnm[r]=m; lnr[r]=1.0/sqrt(v + 1e-5);
  }
  __syncthreads();
  for(int i=t;i<2048;i+=256){
    int r2=i>>9, k=i&511;
    double v=(buf[i]-lnm[r2])*lnr[r2]*(double)g[k]+(double)b[k];
    buf[i]=fmax(v,0.0);
  }
  __syncthreads();
}

// ---------------- MLP head (f64): feat -> assignment f32 (4 rows/block; R12 version) ----------------
__global__ __launch_bounds__(256) void k_mlp(const float* __restrict__ wf, const double* __restrict__ feat,
                                             float* __restrict__ assign_out){
  int r0 = blockIdx.x*4, t = threadIdx.x;
  __shared__ double f0[4*128];
  __shared__ double f1[4*256];
  __shared__ double f2[4*512];
  __shared__ double f3[4*512];
  __shared__ double lnm[4], lnr[4];
  __shared__ double lg[4][8];

  for(int i=t;i<512;i+=256) f0[i] = feat[(size_t)r0*128 + i] * (1.0/256.0);
  __syncthreads();
  {
    double acc[4];
    double bv = (double)wf[WS_FCB + t];
    #pragma unroll
    for(int r=0;r<4;r++) acc[r]=bv;
    for(int k=0;k<128;k++){
      double wv = (double)wf[WS_FCW + t*128 + k];
      #pragma unroll
      for(int r=0;r<4;r++) acc[r]=fma(wv, f0[r*128+k], acc[r]);
    }
    #pragma unroll
    for(int r=0;r<4;r++) f1[r*256+t]=acc[r];
  }
  __syncthreads();
  for(int half=0;half<2;half++){
    int i=t+(half<<8);
    double acc[4];
    double bv=(double)wf[WS_G1B+i];
    #pragma unroll
    for(int r=0;r<4;r++) acc[r]=bv;
    for(int k=0;k<256;k++){
      double wv=(double)wf[WS_G1W + i*256 + k];
      #pragma unroll
      for(int r=0;r<4;r++) acc[r]=fma(wv, f1[r*256+k], acc[r]);
    }
    #pragma unroll
    for(int r=0;r<4;r++) f2[r*512+i]=acc[r];
  }
  __syncthreads();
  ln_relu4(f2, wf+WS_L1G, wf+WS_L1B, lnm, lnr, t);
  for(int half=0;half<2;half++){
    int i=t+(half<<8);
    double acc[4];
    double bv=(double)wf[WS_G2B+i];
    #pragma unroll
    for(int r=0;r<4;r++) acc[r]=bv;
    for(int k=0;k<512;k++){
      double wv=(double)wf[WS_G2W + i*512 + k];
      #pragma unroll
      for(int r=0;r<4;r++) acc[r]=fma(wv, f2[r*512+k], acc[r]);
    }
    #pragma unroll
    for(int r=0;r<4;r++) f3[r*512+i]=acc[r];
  }
  __syncthreads();
  ln_relu4(f3, wf+WS_L2G, wf+WS_L2B, lnm, lnr, t);
  {
    int r=t>>6, j=t&63;
    double pl[8];
    #pragma unroll
    for(int g=0;g<8;g++){
      double s=0.0;
      for(int k=j;k<512;k+=64) s = fma(f3[r*512+k], (double)wf[WS_G3W + g*512 + k], s);
      pl[g]=s;
    }
    #pragma unroll
    for(int off=32;off;off>>=1){
      #pragma unroll
      for(int g=0;g<8;g++) pl[g] += __shfl_down(pl[g], off);
    }
    if(j==0){
      #pragma unroll
      for(int g=0;g<8;g++) lg[r][g] = (pl[g] + (double)wf[WS_G3B+g]) * 2.0; // /TEMP
    }
  }
  __syncthreads();
  if(t<4){
    double m=-1e300;
    #pragma unroll
    for(int g=0;g<8;g++) m = fmax(m, lg[t][g]);
    double e[8], s=0.0;
    #pragma unroll
    for(int g=0;g<8;g++){ e[g]=exp(lg[t][g]-m); s+=e[g]; }
    double inv = 1.0/s;
    int row = r0 + t;
    #pragma unroll
    for(int g=0;g<8;g++) assign_out[row*8+g] = (float)(e[g]*inv);
  }
}

// ---------------- top-32 per (b,g) + gather*scale ----------------
__global__ __launch_bounds__(256) void k_topk(const float* __restrict__ assign, const float* __restrict__ x,
                                              float* __restrict__ out){
  int b = blockIdx.x >> 3, g = blockIdx.x & 7, t = threadIdx.x;
  __shared__ float v[256];
  __shared__ int   id[256];
  v[t] = assign[(b*256+t)*8 + g];
  id[t] = t;
  __syncthreads();
  for(int k=2;k<=256;k<<=1){
    for(int j=k>>1;j>0;j>>=1){
      int ixj = t ^ j;
      if(ixj > t){
        float va=v[t], vb=v[ixj];
        int ia=id[t], ib=id[ixj];
        bool aBefore = (va > vb) || (va == vb && ia < ib);
        bool up = ((t & k) == 0);
        if(up != aBefore){ v[t]=vb; v[ixj]=va; id[t]=ib; id[ixj]=ia; }
      }
      __syncthreads();
    }
  }
  __shared__ float tv[32];
  __shared__ int   ti[32];
  if(t<32){ tv[t]=v[t]; ti[t]=id[t]; }
  __syncthreads();
  const float* xb = x + (size_t)b*65536;
  float* ob = out + (size_t)(b*8+g)*8192;
  for(int i=t;i<8192;i+=256){
    int k=i>>8, pix=i&255;
    ob[i] = tv[k] * xb[ti[k]*256 + pix];
  }
}

// ---------------- launcher ----------------
extern "C" void kernel_launch(void* const* d_in, const int* in_sizes, int n_in,
                              void* d_out, int out_size, void* d_ws, size_t ws_size,
                              hipStream_t stream){
  const float* x = (const float*)d_in[0];
  float*  ws  = (float*)d_ws;
  double* dws = (double*)d_ws;
  float* out = (float*)d_out;
  float* assign_out = out + 1048576;
  float* z2 = (float*)((char*)d_ws + Z2_OFF_B);

  int nS = 0;
  if(ws_size > Z2_OFF_B + 65536){
    unsigned long long avail = (unsigned long long)ws_size - Z2_OFF_B;
    unsigned long long n = avail / 65536ull;
    nS = (n > 4096ull) ? 4096 : (int)n;
  }
  int nR = 4096 - nS;

  const float* g1=(const float*)d_in[3];  const float* b1=(const float*)d_in[4];
  const float* g2=(const float*)d_in[7];  const float* b2=(const float*)d_in[8];
  const float* g3=(const float*)d_in[11]; const float* b3=(const float*)d_in[12];

  WP wp;
  const int map[18] = {1,2,5,6,9,10,13,14,15,16,17,18,19,20,21,22,23,24};
  for(int i=0;i<18;i++) wp.p[i] = (const float*)d_in[map[i]];

  k_zero <<<2162, 256, 0, stream>>>(dws + D_ACC1);
  k_cvt  <<<dim3(1024,18), 256, 0, stream>>>(wp, ws);
  k_p1   <<<4096, 256, 0, stream>>>(x, ws, dws+D_ACC1);
  k_fin  <<<32, 64, 0, stream>>>(dws+D_ACC1, 32, g1, b1, dws+D_AFF1);
  k_p2   <<<4096, 256, 0, stream>>>(x, ws, dws+D_AFF1, dws+D_ACC2, z2, nS);
  k_fin  <<<64, 64, 0, stream>>>(dws+D_ACC2, 64, g2, b2, dws+D_AFF2);
  if(nS > 0) k_cs   <<<2*nS, 256, 0, stream>>>(ws, dws+D_AFF2, dws+D_ACC3, z2);
  if(nR > 0) k_stat3<<<4*nR, 256, 0, stream>>>(x, ws, dws+D_AFF1, dws+D_AFF2, dws+D_ACC3, nS);
  k_fin  <<<128, 64, 0, stream>>>(dws+D_ACC3, 128, g3, b3, dws+D_AFF3);
  if(nS > 0) k_cf  <<<2*nS, 256, 0, stream>>>(ws, dws+D_AFF2, dws+D_AFF3, dws+D_FEAT, z2);
  if(nR > 0) k_p34 <<<4*nR, 256, 0, stream>>>(x, ws, dws+D_AFF1, dws+D_AFF2, dws+D_AFF3, dws+D_FEAT, nS);
  k_mlp  <<<1024, 256, 0, stream>>>(ws, dws+D_FEAT, assign_out);
  k_topk <<<128, 256, 0, stream>>>(assign_out, x, out);
}